// Round 1
// baseline (1710.612 us; speedup 1.0000x reference)
//
#include <hip/hip_runtime.h>
#include <math.h>

// Problem constants (from reference):
//   B=16, C=16, T=40000, N_FFT=64, FFT_STRIDE=32 -> num_frames=1249
//   num_freqs=33, WINDOW_LENGTH/FFT_STRIDE=32 frames/window, step=4 -> 305 windows
//   ||hann_nonperiodic(64)||^2 = 23.625 exactly (analytic).
#define NFRAMES 1249
#define NFREQ   33
#define NWIN    305
#define NCH     16
#define T_IN    40000
#define NSWEEP  8

// ---------------- Kernel A: windowed rfft-64 -> spec[b][f][frame][c] ----------------
__global__ __launch_bounds__(256) void kspec(const float* __restrict__ x,
                                             float2* __restrict__ spec) {
    __shared__ float2 twid[64];
    __shared__ float  win[64];
    int tid = threadIdx.x;
    if (tid < 64) {
        const float PI2 = 6.28318530717958647692f;
        float ang = (PI2 / 64.0f) * (float)tid;
        twid[tid] = make_float2(cosf(ang), -sinf(ang));      // e^{-2pi i k/64}
        float wv  = 0.5f * (1.0f - cosf((PI2 / 63.0f) * (float)tid));
        win[tid]  = wv * (1.0f / sqrtf(23.625f));            // fold 1/wnorm into window
    }
    __syncthreads();

    int fl = tid & 15;           // frame-local (consecutive lanes -> consecutive frames)
    int c  = tid >> 4;           // channel
    int b  = blockIdx.y;
    int frame = blockIdx.x * 16 + fl;
    if (frame >= NFRAMES) return;

    const float* xp = x + (size_t)(b * 16 + c) * T_IN + (size_t)frame * 32;
    float xw[64];
    #pragma unroll
    for (int k = 0; k < 16; k++) {
        float4 v = reinterpret_cast<const float4*>(xp)[k];
        xw[4*k+0] = v.x * win[4*k+0];
        xw[4*k+1] = v.y * win[4*k+1];
        xw[4*k+2] = v.z * win[4*k+2];
        xw[4*k+3] = v.w * win[4*k+3];
    }
    for (int f = 0; f < NFREQ; f++) {
        float re = 0.0f, im = 0.0f;
        #pragma unroll
        for (int n = 0; n < 64; n++) {
            float2 tw = twid[(f * n) & 63];
            re = fmaf(xw[n], tw.x, re);
            im = fmaf(xw[n], tw.y, im);
        }
        spec[((size_t)(b * NFREQ + f) * NFRAMES + frame) * NCH + c] = make_float2(re, im);
    }
}

// ------- Kernel B: CSD (|csd|^2) + one-sided Jacobi eig + V log(L) V^T -------
// 16 lanes per matrix; lane t owns column t. 16 matrices per 256-thread block.
__global__ __launch_bounds__(256) void keig(const float2* __restrict__ spec,
                                            float* __restrict__ outC, int direct) {
    __shared__ float Gs[16][16][17];   // [mat-in-block][col][elem], stride 17: conflict-free
    __shared__ float Hs[16][16][17];
    int tid  = threadIdx.x;
    int lane = tid & 63;
    int matl = tid >> 4;               // 0..15 (wave*4 + group)
    int t    = tid & 15;               // column owned by this lane
    int mat  = blockIdx.x * 16 + matl; // < 161040 exactly (10065 blocks)
    int wwin = mat % NWIN;
    int bf   = mat / NWIN;             // b*33 + f

    const float2* zb = spec + ((size_t)bf * NFRAMES + (size_t)wwin * 4) * NCH;

    // --- CSD accumulation: csd[c][t] = sum_s z_c[s] * conj(z_t[s]) ---
    float cr[16], ci[16];
    #pragma unroll
    for (int c2 = 0; c2 < 16; c2++) { cr[c2] = 0.0f; ci[c2] = 0.0f; }
    for (int chunk = 0; chunk < 4; chunk++) {
        float zx[8], zy[8];
        #pragma unroll
        for (int s = 0; s < 8; s++) {
            float2 z = zb[(size_t)(chunk * 8 + s) * NCH + t];   // coalesced (lane=c)
            zx[s] = z.x; zy[s] = z.y;
        }
        #pragma unroll
        for (int c2 = 0; c2 < 16; c2++) {
            int src = (lane & 48) | c2;    // broadcast channel c2 within 16-group
            #pragma unroll
            for (int s = 0; s < 8; s++) {
                float zcx = __shfl(zx[s], src);
                float zcy = __shfl(zy[s], src);
                cr[c2] = fmaf(zcx, zx[s], fmaf(zcy, zy[s], cr[c2]));
                ci[c2] = fmaf(zcy, zx[s], fmaf(-zcx, zy[s], ci[c2]));
            }
        }
    }
    // A[c][t] = |csd/32|^2  (fold 1/32^2)
    float a[16];
    #pragma unroll
    for (int c2 = 0; c2 < 16; c2++)
        a[c2] = (cr[c2] * cr[c2] + ci[c2] * ci[c2]) * (1.0f / 1024.0f);

    // --- One-sided Jacobi on columns of A (A is sym PSD => SVD == eigendecomp).
    // XOR-pair ordering: no dynamic register indexing anywhere.
    for (int sweep = 0; sweep < NSWEEP; sweep++) {
        for (int m = 1; m < 16; m++) {
            int pl = lane ^ m;
            float app = 0.0f;
            #pragma unroll
            for (int i = 0; i < 16; i++) app = fmaf(a[i], a[i], app);
            float aqq = __shfl(app, pl);
            float bcol[16];
            #pragma unroll
            for (int i = 0; i < 16; i++) bcol[i] = __shfl(a[i], pl);
            float apq = 0.0f;
            #pragma unroll
            for (int i = 0; i < 16; i++) apq = fmaf(a[i], bcol[i], apq);
            bool isP = t < (t ^ m);
            float npp = isP ? app : aqq;
            float nqq = isP ? aqq : app;
            if (apq * apq > npp * nqq * 1e-14f) {   // identical decision in both partners
                float tau = (nqq - npp) / (2.0f * apq);
                float tt  = copysignf(1.0f, tau) / (fabsf(tau) + sqrtf(fmaf(tau, tau, 1.0f)));
                float cc  = 1.0f / sqrtf(fmaf(tt, tt, 1.0f));
                float ss  = tt * cc;
                float se  = isP ? -ss : ss;         // g_p' = c g_p - s g_q ; g_q' = s g_p + c g_q
                #pragma unroll
                for (int i = 0; i < 16; i++) a[i] = fmaf(se, bcol[i], cc * a[i]);
            }
        }
    }

    // --- eigenvalue = ||col||, f = log(lambda) = 0.5*log(||col||^2); weight w = f/||col||^2
    float sqn = 0.0f;
    #pragma unroll
    for (int i = 0; i < 16; i++) sqn = fmaf(a[i], a[i], sqn);
    float wgt = 0.0f;
    if (sqn > 1e-30f) wgt = 0.5f * logf(sqn) / sqn;   // degenerate -> 0 (nan_to_num semantics)

    #pragma unroll
    for (int i = 0; i < 16; i++) {
        Gs[matl][t][i] = a[i];
        Hs[matl][t][i] = wgt * a[i];
    }
    __syncthreads();

    // C[i][t] = sum_j G[j][i] * H[j][t]  (G read broadcast; H read lane-consecutive)
    float acc[16];
    #pragma unroll
    for (int i = 0; i < 16; i++) acc[i] = 0.0f;
    #pragma unroll
    for (int j = 0; j < 16; j++) {
        float hjt = Hs[matl][j][t];
        #pragma unroll
        for (int i = 0; i < 16; i++) acc[i] = fmaf(Gs[matl][j][i], hjt, acc[i]);
    }

    if (!direct) {
        float* op = outC + (size_t)mat * 256;          // Cws[bf][w][cd], coalesced
        #pragma unroll
        for (int i = 0; i < 16; i++) op[i * 16 + t] = acc[i];
    } else {
        float* op = outC + (size_t)bf * 256 * NWIN + wwin;  // out[bf][cd][w], scattered
        #pragma unroll
        for (int i = 0; i < 16; i++) op[(size_t)(i * 16 + t) * NWIN] = acc[i];
    }
}

// ---------------- Kernel C: per-bf transpose [w][cd] -> [cd][w] ----------------
__global__ __launch_bounds__(256) void ktrans(const float* __restrict__ in,
                                              float* __restrict__ out) {
    __shared__ float tile[32][33];
    int bf = blockIdx.z;
    const float* ip = in  + (size_t)bf * NWIN * 256;
    float*       op = out + (size_t)bf * 256 * NWIN;
    int tx = threadIdx.x, ty = threadIdx.y;
    int w0 = blockIdx.x * 32, cd0 = blockIdx.y * 32;
    #pragma unroll
    for (int r = 0; r < 32; r += 8) {
        int w = w0 + ty + r;
        if (w < NWIN) tile[ty + r][tx] = ip[(size_t)w * 256 + cd0 + tx];
    }
    __syncthreads();
    #pragma unroll
    for (int r = 0; r < 32; r += 8) {
        int cd = cd0 + ty + r;
        int w  = w0 + tx;
        if (w < NWIN) op[(size_t)cd * NWIN + w] = tile[tx][ty + r];
    }
}

extern "C" void kernel_launch(void* const* d_in, const int* in_sizes, int n_in,
                              void* d_out, int out_size, void* d_ws, size_t ws_size,
                              hipStream_t stream) {
    const float* x = (const float*)d_in[0];
    float* out = (float*)d_out;

    float2* spec = (float2*)d_ws;
    const size_t specBytes = (size_t)16 * NFREQ * NFRAMES * NCH * sizeof(float2); // 84,412,416
    const size_t cBytes    = (size_t)161040 * 256 * sizeof(float);                // 164,904,960
    float* Cws = (float*)((char*)d_ws + specBytes);
    int full = (ws_size >= specBytes + cBytes) ? 1 : 0;

    kspec<<<dim3(79, 16), 256, 0, stream>>>(x, spec);
    if (full) {
        keig<<<dim3(10065), 256, 0, stream>>>(spec, Cws, 0);
        ktrans<<<dim3(10, 8, 528), dim3(32, 8), 0, stream>>>(Cws, out);
    } else {
        keig<<<dim3(10065), 256, 0, stream>>>(spec, out, 1);
    }
}

// Round 2
// 1401.737 us; speedup vs baseline: 1.2204x; 1.2204x over previous
//
#include <hip/hip_runtime.h>
#include <math.h>

// B=16, C=16, T=40000, N_FFT=64, FFT_STRIDE=32 -> 1249 frames
// 33 freqs, 32 frames/window, step 4 -> 305 windows
// ||hann(64)||^2 = 23.625; fold 1/sqrt(23.625*32) into window so CSD/32 and
// the |.|^2 /1024 scaling are free.
#define NFRAMES 1249
#define NFREQ   33
#define NWIN    305
#define NCH     16
#define T_IN    40000
#define NSWEEP  6

// ---------------- Kernel A: windowed rfft-64 -> spec[b][f][frame][c] ----------------
__global__ __launch_bounds__(256) void kspec(const float* __restrict__ x,
                                             float2* __restrict__ spec) {
    __shared__ float2 twid[64];
    __shared__ float  win[64];
    int tid = threadIdx.x;
    if (tid < 64) {
        const float PI2 = 6.28318530717958647692f;
        float ang = (PI2 / 64.0f) * (float)tid;
        twid[tid] = make_float2(cosf(ang), -sinf(ang));      // e^{-2pi i k/64}
        float wv  = 0.5f * (1.0f - cosf((PI2 / 63.0f) * (float)tid));
        win[tid]  = wv * (1.0f / sqrtf(23.625f * 32.0f));    // 1/wnorm and 1/sqrt(ws) folded
    }
    __syncthreads();

    int fl = tid & 15;
    int c  = tid >> 4;
    int b  = blockIdx.y;
    int frame = blockIdx.x * 16 + fl;
    if (frame >= NFRAMES) return;

    const float* xp = x + (size_t)(b * 16 + c) * T_IN + (size_t)frame * 32;
    float xw[64];
    #pragma unroll
    for (int k = 0; k < 16; k++) {
        float4 v = reinterpret_cast<const float4*>(xp)[k];
        xw[4*k+0] = v.x * win[4*k+0];
        xw[4*k+1] = v.y * win[4*k+1];
        xw[4*k+2] = v.z * win[4*k+2];
        xw[4*k+3] = v.w * win[4*k+3];
    }
    for (int f = 0; f < NFREQ; f++) {
        float re = 0.0f, im = 0.0f;
        #pragma unroll
        for (int n = 0; n < 64; n++) {
            float2 tw = twid[(f * n) & 63];
            re = fmaf(xw[n], tw.x, re);
            im = fmaf(xw[n], tw.y, im);
        }
        spec[((size_t)(b * NFREQ + f) * NFRAMES + frame) * NCH + c] = make_float2(re, im);
    }
}

// ------- Kernel B: CSD + one-sided Jacobi eig + V log(L) V^T, direct output -------
// Block = (bf, wtile): 16 matrices with consecutive w. 16 lanes/matrix.
// LDS: single G buffer (reused as output-staging tile) + per-column weights.
__global__ __launch_bounds__(256) void keig(const float2* __restrict__ spec,
                                            float* __restrict__ out) {
    __shared__ float Gs[16 * 16 * 17];   // Gs[matl][col][row]; reused as tile[256][17]
    __shared__ float wgts[16][16];
    int tid  = threadIdx.x;
    int lane = tid & 63;
    int matl = tid >> 4;
    int t    = tid & 15;
    int w0   = blockIdx.x * 16;          // wtile*16; blockIdx.x in [0,20)
    int bf   = blockIdx.y;               // b*33 + f
    int wwin = min(w0 + matl, NWIN - 1); // clamp tail (w=305..319 are dead, stores guarded)

    const float2* zb = spec + ((size_t)bf * NFRAMES + (size_t)wwin * 4) * NCH;

    // --- CSD: csd[c][t] = sum_s z_c[s] conj(z_t[s]) (scaling pre-folded in kspec) ---
    float cr[16], ci[16];
    #pragma unroll
    for (int c2 = 0; c2 < 16; c2++) { cr[c2] = 0.0f; ci[c2] = 0.0f; }
    for (int chunk = 0; chunk < 4; chunk++) {
        float zx[8], zy[8];
        #pragma unroll
        for (int s = 0; s < 8; s++) {
            float2 z = zb[(size_t)(chunk * 8 + s) * NCH + t];
            zx[s] = z.x; zy[s] = z.y;
        }
        #pragma unroll
        for (int c2 = 0; c2 < 16; c2++) {
            int src = (lane & 48) | c2;
            #pragma unroll
            for (int s = 0; s < 8; s++) {
                float zcx = __shfl(zx[s], src);
                float zcy = __shfl(zy[s], src);
                cr[c2] = fmaf(zcx, zx[s], fmaf(zcy, zy[s], cr[c2]));
                ci[c2] = fmaf(zcy, zx[s], fmaf(-zcx, zy[s], ci[c2]));
            }
        }
    }
    float a[16];
    #pragma unroll
    for (int c2 = 0; c2 < 16; c2++)
        a[c2] = fmaf(cr[c2], cr[c2], ci[c2] * ci[c2]);   // A = |csd/ws|^2

    // --- One-sided Jacobi, maintained squared column norms, early exit ---
    #pragma unroll 1
    for (int sweep = 0; sweep < NSWEEP; sweep++) {
        float app = 0.0f;                 // refresh norm each sweep (kills fma drift)
        #pragma unroll
        for (int i = 0; i < 16; i++) app = fmaf(a[i], a[i], app);
        int any = 0;
        for (int m = 1; m < 16; m++) {
            int pl = lane ^ m;
            float aqq = __shfl(app, pl);
            float bcol[16];
            #pragma unroll
            for (int i = 0; i < 16; i++) bcol[i] = __shfl(a[i], pl);
            float apq = 0.0f;
            #pragma unroll
            for (int i = 0; i < 16; i++) apq = fmaf(a[i], bcol[i], apq);
            bool isP = t < (t ^ m);
            float npp = isP ? app : aqq;
            float nqq = isP ? aqq : app;
            if (apq * apq > npp * nqq * 1e-12f) {   // same decision in both partners
                float tau = (nqq - npp) / (2.0f * apq);
                float tt  = copysignf(1.0f, tau) / (fabsf(tau) + sqrtf(fmaf(tau, tau, 1.0f)));
                float cc  = 1.0f / sqrtf(fmaf(tt, tt, 1.0f));
                float ss  = tt * cc;
                float se  = isP ? -ss : ss;
                #pragma unroll
                for (int i = 0; i < 16; i++) a[i] = fmaf(se, bcol[i], cc * a[i]);
                app = fmaf(isP ? -tt : tt, apq, app);  // two-sided Jacobi norm identity
                any = 1;
            }
        }
        if (!__any(any)) break;
    }

    // lambda = ||col||; wgt = log(lambda)/lambda^2 = 0.5*log(sqn)/sqn
    float sqn = 0.0f;
    #pragma unroll
    for (int i = 0; i < 16; i++) sqn = fmaf(a[i], a[i], sqn);
    float wgt = 0.0f;
    if (sqn > 1e-30f) wgt = 0.5f * logf(sqn) / sqn;    // nan_to_num(log, nan/neginf->0)

    float* G = &Gs[0];
    #pragma unroll
    for (int i = 0; i < 16; i++) G[(matl * 16 + t) * 17 + i] = a[i];
    wgts[matl][t] = wgt;
    __syncthreads();

    // C[i][t] = sum_j wgt_j * G[j][i] * G[j][t]
    float acc[16];
    #pragma unroll
    for (int i = 0; i < 16; i++) acc[i] = 0.0f;
    #pragma unroll
    for (int j = 0; j < 16; j++) {
        float hjt = wgts[matl][j] * G[(matl * 16 + j) * 17 + t];
        #pragma unroll
        for (int i = 0; i < 16; i++)
            acc[i] = fmaf(G[(matl * 16 + j) * 17 + i], hjt, acc[i]);
    }
    __syncthreads();                       // all G reads done; reuse LDS as tile[256][17]

    #pragma unroll
    for (int i = 0; i < 16; i++) G[(i * 16 + t) * 17 + matl] = acc[i];  // tile[cd][w]=C
    __syncthreads();

    // write out[bf][cd][w0+w]: per wave 4 runs of 16 consecutive floats
    int w  = tid & 15;
    int cdr = tid >> 4;
    if (w0 + w < NWIN) {
        float* op = out + (size_t)bf * (256 * NWIN) + (size_t)(w0 + w);
        #pragma unroll
        for (int k = 0; k < 16; k++) {
            int cd = k * 16 + cdr;
            op[(size_t)cd * NWIN] = G[cd * 17 + w];
        }
    }
}

extern "C" void kernel_launch(void* const* d_in, const int* in_sizes, int n_in,
                              void* d_out, int out_size, void* d_ws, size_t ws_size,
                              hipStream_t stream) {
    const float* x = (const float*)d_in[0];
    float* out = (float*)d_out;
    float2* spec = (float2*)d_ws;        // 16*33*1249*16 float2 = 84,412,416 B

    kspec<<<dim3(79, 16), 256, 0, stream>>>(x, spec);
    keig<<<dim3(20, 528), 256, 0, stream>>>(spec, out);   // 20 wtiles x 528 bf
}